// Round 1
// baseline (1120.456 us; speedup 1.0000x reference)
//
#include <hip/hip_runtime.h>
#include <type_traits>

// MI355X / gfx950. Wave = 64. MFMA fp16 16x16x32.
// Layouts (guide-verified, m89/m91): A[m=lane&15][k=quad*8+j],
// B[n=lane&15][k=quad*8+j] (i.e. row-major N x K operand), C/D: col=lane&15,
// row=quad*4+reg. k-grouping is permutation-invariant as long as A and B agree.

typedef _Float16 half8 __attribute__((ext_vector_type(8)));
typedef float    floatx4 __attribute__((ext_vector_type(4)));

#define MFMA16(a, b, c) __builtin_amdgcn_mfma_f32_16x16x32_f16((a), (b), (c), 0, 0, 0)

#define D_MODEL 1024
#define S_LEN   2048
#define NHEAD   16
#define DEPTH   64
#define BATCH   2

// ---------------------------------------------------------------------------
// Linear kernel: Y = X @ W^T + b.   X: [4096 x 1024] (TIN), W: [1024 x 1024] fp32.
// MODE 0: output fp16, head-split [B][H][S][depth] (for Q/K/V).
// MODE 1: output fp32, plain [4096 x 1024] (final projection).
// Block 256 (4 waves), tile 64x64, BK=32.
// ---------------------------------------------------------------------------
template <int MODE, typename TIN>
__global__ __launch_bounds__(256, 2) void lin_kernel(
    const TIN* __restrict__ X, const float* __restrict__ W,
    const float* __restrict__ bias, void* __restrict__ outp)
{
    __shared__ _Float16 A_lds[64 * 40];   // +8 halves pad: conflict-free b128
    __shared__ _Float16 B_lds[64 * 40];

    const int tid  = threadIdx.x;
    const int lane = tid & 63;
    const int wv   = tid >> 6;            // 0..3, n-strip
    const int r15  = lane & 15;
    const int quad = lane >> 4;
    const int bn   = blockIdx.x;          // 0..15
    const int bm   = blockIdx.y;          // 0..63
    const int srow = tid >> 2;            // 0..63 staging row
    const int sseg = tid & 3;             // 8-element k segment

    const TIN*   ax = X + (size_t)(bm * 64 + srow) * 1024 + sseg * 8;
    const float* bx = W + (size_t)(bn * 64 + srow) * 1024 + sseg * 8;
    _Float16* asl = &A_lds[srow * 40 + sseg * 8];
    _Float16* bsl = &B_lds[srow * 40 + sseg * 8];

    floatx4 acc[4];
#pragma unroll
    for (int t = 0; t < 4; ++t) acc[t] = floatx4{0.f, 0.f, 0.f, 0.f};

    for (int k0 = 0; k0 < 1024; k0 += 32) {
        half8 av, bv8;
        if constexpr (std::is_same<TIN, _Float16>::value) {
            av = *(const half8*)(ax + k0);
        } else {
            floatx4 f0 = *(const floatx4*)(ax + k0);
            floatx4 f1 = *(const floatx4*)(ax + k0 + 4);
#pragma unroll
            for (int i = 0; i < 4; ++i) { av[i] = (_Float16)f0[i]; av[i + 4] = (_Float16)f1[i]; }
        }
        {
            floatx4 f0 = *(const floatx4*)(bx + k0);
            floatx4 f1 = *(const floatx4*)(bx + k0 + 4);
#pragma unroll
            for (int i = 0; i < 4; ++i) { bv8[i] = (_Float16)f0[i]; bv8[i + 4] = (_Float16)f1[i]; }
        }
        __syncthreads();           // previous iteration's frag reads done
        *(half8*)asl = av;
        *(half8*)bsl = bv8;
        __syncthreads();
        half8 bf = *(const half8*)&B_lds[(wv * 16 + r15) * 40 + quad * 8];
#pragma unroll
        for (int t = 0; t < 4; ++t) {
            half8 af = *(const half8*)&A_lds[(t * 16 + r15) * 40 + quad * 8];
            acc[t] = MFMA16(af, bf, acc[t]);
        }
    }

    const int gcol = bn * 64 + wv * 16 + r15;
    const float bb = bias[gcol];
    if constexpr (MODE == 0) {
        _Float16* o = (_Float16*)outp;
        const int hh = gcol >> 6, dd = gcol & 63;
#pragma unroll
        for (int t = 0; t < 4; ++t) {
#pragma unroll
            for (int r = 0; r < 4; ++r) {
                int grow = bm * 64 + t * 16 + quad * 4 + r;   // = b*2048 + s
                int b_ = grow >> 11, s = grow & 2047;
                o[((size_t)((b_ * 16 + hh) * 2048 + s)) * 64 + dd] =
                    (_Float16)(acc[t][r] + bb);
            }
        }
    } else {
        float* o = (float*)outp;
#pragma unroll
        for (int t = 0; t < 4; ++t) {
#pragma unroll
            for (int r = 0; r < 4; ++r) {
                int grow = bm * 64 + t * 16 + quad * 4 + r;
                o[(size_t)grow * 1024 + gcol] = acc[t][r] + bb;
            }
        }
    }
}

// ---------------------------------------------------------------------------
// Attention kernel: per block = (b, h, 16 q-rows). Block 256 = 4 waves.
// Phase 1: S = QK^T/8 in registers (32 x float4 per lane, C-layout).
// Phase 2: softmax (shuffle + LDS cross-wave reduce). Writes fp32 weights to
//          d_out and fp16 weights to LDS (A-layout source for PV).
// Phase 3: PV with V transposed into LDS; wave w owns d-columns [16w,16w+16).
// mask*1e-9 from the reference is <=1e-9 on O(1) logits -> numerically dropped.
// ---------------------------------------------------------------------------
__global__ __launch_bounds__(256, 2) void attn_kernel(
    const _Float16* __restrict__ Q, const _Float16* __restrict__ K,
    const _Float16* __restrict__ V, float* __restrict__ wout,
    _Float16* __restrict__ attn_out)
{
    __shared__ _Float16 stage[64 * 72];     // K tile [64 key][64+8 d] / Vt [64 d][64+8 key]
    __shared__ _Float16 w_lds[16 * 2056];   // weights fp16, stride 2056 (16B-aligned, spread banks)
    __shared__ float red[2][4][16];         // cross-wave max / sum

    const int tid  = threadIdx.x;
    const int lane = tid & 63;
    const int wv   = tid >> 6;      // 0..3
    const int r15  = lane & 15;
    const int quad = lane >> 4;
    const int qb   = blockIdx.x;    // 0..127 q-tile
    const int h    = blockIdx.y;
    const int b    = blockIdx.z;

    const size_t hoff = ((size_t)(b * 16 + h)) * S_LEN * DEPTH;
    const _Float16* Qh = Q + hoff + (size_t)qb * 16 * DEPTH;
    const _Float16* Kh = K + hoff;
    const _Float16* Vh = V + hoff;

    // Q fragments (row = r15, k = depth)
    half8 q0 = *(const half8*)(Qh + r15 * 64 + quad * 8);
    half8 q1 = *(const half8*)(Qh + r15 * 64 + 32 + quad * 8);

    const int srow = tid >> 2;      // K staging: row (key), 0..63
    const int sseg = tid & 3;

    floatx4 S[32];

    // ---- Phase 1: logits ----
#pragma unroll
    for (int kt = 0; kt < 32; ++kt) {
        const _Float16* src = Kh + (size_t)(kt * 64 + srow) * 64 + sseg * 16;
        half8 v0 = *(const half8*)src;
        half8 v1 = *(const half8*)(src + 8);
        __syncthreads();
        *(half8*)&stage[srow * 72 + sseg * 16] = v0;
        *(half8*)&stage[srow * 72 + sseg * 16 + 8] = v1;
        __syncthreads();
        half8 b0 = *(const half8*)&stage[(wv * 16 + r15) * 72 + quad * 8];
        half8 b1 = *(const half8*)&stage[(wv * 16 + r15) * 72 + 32 + quad * 8];
        floatx4 z = floatx4{0.f, 0.f, 0.f, 0.f};
        z = MFMA16(q0, b0, z);
        z = MFMA16(q1, b1, z);
        S[kt] = z;
    }

    // ---- Phase 2: softmax ----
    float pm[4] = {-1e30f, -1e30f, -1e30f, -1e30f};
#pragma unroll
    for (int kt = 0; kt < 32; ++kt) {
#pragma unroll
        for (int j = 0; j < 4; ++j) {
            S[kt][j] *= 0.125f;                      // 1/sqrt(64)
            pm[j] = fmaxf(pm[j], S[kt][j]);
        }
    }
#pragma unroll
    for (int m = 1; m <= 8; m <<= 1) {
#pragma unroll
        for (int j = 0; j < 4; ++j) pm[j] = fmaxf(pm[j], __shfl_xor(pm[j], m, 64));
    }
#pragma unroll
    for (int j = 0; j < 4; ++j)
        if (r15 == j) red[0][wv][quad * 4 + j] = pm[j];
    __syncthreads();
    float gm[4];
#pragma unroll
    for (int j = 0; j < 4; ++j) {
        int row = quad * 4 + j;
        gm[j] = fmaxf(fmaxf(red[0][0][row], red[0][1][row]),
                      fmaxf(red[0][2][row], red[0][3][row]));
    }
    float ps[4] = {0.f, 0.f, 0.f, 0.f};
#pragma unroll
    for (int kt = 0; kt < 32; ++kt) {
#pragma unroll
        for (int j = 0; j < 4; ++j) {
            float e = __expf(S[kt][j] - gm[j]);
            S[kt][j] = e;
            ps[j] += e;
        }
    }
#pragma unroll
    for (int m = 1; m <= 8; m <<= 1) {
#pragma unroll
        for (int j = 0; j < 4; ++j) ps[j] += __shfl_xor(ps[j], m, 64);
    }
#pragma unroll
    for (int j = 0; j < 4; ++j)
        if (r15 == j) red[1][wv][quad * 4 + j] = ps[j];
    __syncthreads();
    float gl[4];
#pragma unroll
    for (int j = 0; j < 4; ++j) {
        int row = quad * 4 + j;
        gl[j] = 1.0f / (red[1][0][row] + red[1][1][row] + red[1][2][row] + red[1][3][row]);
    }

    // weights: fp32 -> global, fp16 -> LDS
    float* wrow = wout + (((size_t)(b * 16 + h)) * S_LEN + (size_t)qb * 16) * S_LEN;
#pragma unroll
    for (int kt = 0; kt < 32; ++kt) {
#pragma unroll
        for (int j = 0; j < 4; ++j) {
            float val = S[kt][j] * gl[j];
            int row = quad * 4 + j;
            int key = kt * 64 + wv * 16 + r15;
            wrow[(size_t)row * S_LEN + key] = val;
            w_lds[row * 2056 + key] = (_Float16)val;
        }
    }
    __syncthreads();

    // ---- Phase 3: PV ----
    const int vkey  = tid & 63;     // staging: consecutive lanes -> consecutive keys
    const int vdseg = tid >> 6;     // 16-d segment
    floatx4 oacc = floatx4{0.f, 0.f, 0.f, 0.f};
    for (int vt = 0; vt < 32; ++vt) {
        const _Float16* vsrc = Vh + (size_t)(vt * 64 + vkey) * 64 + vdseg * 16;
        half8 v0 = *(const half8*)vsrc;
        half8 v1 = *(const half8*)(vsrc + 8);
        __syncthreads();            // prior tile's frag reads done
#pragma unroll
        for (int jj = 0; jj < 8; ++jj) {
            stage[(vdseg * 16 + jj) * 72 + vkey]     = v0[jj];   // Vt[d][key]
            stage[(vdseg * 16 + 8 + jj) * 72 + vkey] = v1[jj];
        }
        __syncthreads();
#pragma unroll
        for (int ks = 0; ks < 2; ++ks) {
            half8 af = *(const half8*)&w_lds[r15 * 2056 + vt * 64 + ks * 32 + quad * 8];
            half8 bf = *(const half8*)&stage[(wv * 16 + r15) * 72 + ks * 32 + quad * 8];
            oacc = MFMA16(af, bf, oacc);
        }
    }

    // attn output, fp16, layout [b*2048+s][h*64+d] (= GEMM input for Wo)
    _Float16* ao = attn_out + ((size_t)(b * S_LEN + qb * 16)) * D_MODEL + h * 64 + wv * 16;
#pragma unroll
    for (int r = 0; r < 4; ++r)
        ao[(size_t)(quad * 4 + r) * D_MODEL + r15] = (_Float16)oacc[r];
}

// ---------------------------------------------------------------------------
extern "C" void kernel_launch(void* const* d_in, const int* in_sizes, int n_in,
                              void* d_out, int out_size, void* d_ws, size_t ws_size,
                              hipStream_t stream)
{
    const float* q  = (const float*)d_in[0];
    const float* k  = (const float*)d_in[1];
    const float* v  = (const float*)d_in[2];
    // d_in[3] = mask: contributes mask*1e-9 <= 1e-9 to O(1) logits -> dropped.
    const float* Wq = (const float*)d_in[4];
    const float* bq = (const float*)d_in[5];
    const float* Wk = (const float*)d_in[6];
    const float* bk = (const float*)d_in[7];
    const float* Wv = (const float*)d_in[8];
    const float* bv = (const float*)d_in[9];
    const float* Wo = (const float*)d_in[10];
    const float* bo = (const float*)d_in[11];

    const size_t NTOK = (size_t)BATCH * S_LEN * D_MODEL;   // 4194304
    _Float16* Qw = (_Float16*)d_ws;
    _Float16* Kw = Qw + NTOK;
    _Float16* Vw = Kw + NTOK;
    _Float16* Aw = Vw + NTOK;

    float* out  = (float*)d_out;                 // [2,2048,1024]
    float* wout = out + NTOK;                    // [2,16,2048,2048]

    dim3 blk(256);
    dim3 lin_grid(16, 64);
    lin_kernel<0, float><<<lin_grid, blk, 0, stream>>>(q, Wq, bq, (void*)Qw);
    lin_kernel<0, float><<<lin_grid, blk, 0, stream>>>(k, Wk, bk, (void*)Kw);
    lin_kernel<0, float><<<lin_grid, blk, 0, stream>>>(v, Wv, bv, (void*)Vw);
    attn_kernel<<<dim3(128, 16, 2), blk, 0, stream>>>(Qw, Kw, Vw, wout, Aw);
    lin_kernel<1, _Float16><<<lin_grid, blk, 0, stream>>>(Aw, Wo, bo, (void*)out);
}

// Round 2
// 991.884 us; speedup vs baseline: 1.1296x; 1.1296x over previous
//
#include <hip/hip_runtime.h>

// MI355X / gfx950. Wave = 64. MFMA fp16 16x16x32.
// Verified layouts (m89/m91): A[m=lane&15][k=quad*8+j], B[n=lane&15][k=quad*8+j],
// C/D: col=lane&15, row=quad*4+reg. k-grouping permutation-invariant if A/B agree.

typedef _Float16 half8 __attribute__((ext_vector_type(8)));
typedef float    floatx4 __attribute__((ext_vector_type(4)));

#define MFMA16(a, b, c) __builtin_amdgcn_mfma_f32_16x16x32_f16((a), (b), (c), 0, 0, 0)

#define D_MODEL 1024
#define S_LEN   2048
#define NHEAD   16
#define DEPTH   64
#define BATCH   2

// async global->LDS, 16B per lane. LDS dest = wave-uniform base + lane*16;
// per-lane lds pointers below are constructed to satisfy exactly that.
__device__ __forceinline__ void gld_lds16(const _Float16* g, _Float16* l) {
    __builtin_amdgcn_global_load_lds(
        (const __attribute__((address_space(1))) unsigned int*)g,
        (__attribute__((address_space(3))) unsigned int*)l, 16, 0, 0);
}

// ---------------------------------------------------------------------------
// fp32 -> fp16 convert, 8 elements/thread.
// ---------------------------------------------------------------------------
__global__ void cvt_kernel(const float* __restrict__ src, _Float16* __restrict__ dst, int n8) {
    int i = blockIdx.x * 256 + threadIdx.x;
    if (i < n8) {
        const floatx4* s = (const floatx4*)src + (size_t)i * 2;
        floatx4 f0 = s[0], f1 = s[1];
        half8 h;
#pragma unroll
        for (int j = 0; j < 4; ++j) { h[j] = (_Float16)f0[j]; h[4 + j] = (_Float16)f1[j]; }
        *((half8*)dst + i) = h;
    }
}

// ---------------------------------------------------------------------------
// GEMM: Y = X @ W^T + b. X:[4096x1024] fp16, W:[1024x1024] fp16 (row-major).
// 128x128 tile, BK=32, 4 waves (2x2), global_load_lds width=16 (m97 structure).
// MODE 0: fp16 out, head-split [B][H][S][D]     (Q, K projections)
// MODE 2: fp16 out, head-split transposed [B][H][D][S]  (V projection)
// MODE 1: fp32 out, [4096][1024]                (final projection)
// ---------------------------------------------------------------------------
template <int MODE>
__global__ __launch_bounds__(256) void gemm_kernel(
    const _Float16* __restrict__ X, const _Float16* __restrict__ W,
    const float* __restrict__ bias, void* __restrict__ outp)
{
    __shared__ _Float16 A_lds[128 * 32];   // unpadded: required by global_load_lds
    __shared__ _Float16 B_lds[128 * 32];

    const int tid  = threadIdx.x;
    const int lane = tid & 63;
    const int w    = tid >> 6;
    const int r15  = lane & 15;
    const int quad = lane >> 4;
    const int wr   = w >> 1, wc = w & 1;
    const int bn   = blockIdx.x;           // 0..7
    const int bm   = blockIdx.y;           // 0..31

    // staging: issue j covers rows j*64 + w*16 + lane/4, 16B segment lane&3
    const int srow = w * 16 + (lane >> 2);
    const int sseg = lane & 3;
    const _Float16* ag = X + (size_t)(bm * 128 + srow) * 1024 + sseg * 8;
    const _Float16* bg = W + (size_t)(bn * 128 + srow) * 1024 + sseg * 8;
    _Float16* al = &A_lds[srow * 32 + sseg * 8];
    _Float16* bl = &B_lds[srow * 32 + sseg * 8];

    floatx4 acc[4][4];
#pragma unroll
    for (int t = 0; t < 4; ++t)
#pragma unroll
        for (int u = 0; u < 4; ++u) acc[t][u] = floatx4{0.f, 0.f, 0.f, 0.f};

    for (int k0 = 0; k0 < 1024; k0 += 32) {
        __syncthreads();                               // prev iter frag reads done
        gld_lds16(ag + k0, al);
        gld_lds16(ag + k0 + (size_t)64 * 1024, al + 64 * 32);
        gld_lds16(bg + k0, bl);
        gld_lds16(bg + k0 + (size_t)64 * 1024, bl + 64 * 32);
        __syncthreads();                               // loads landed (vmcnt drain)
        half8 a[4], bf[4];
#pragma unroll
        for (int t = 0; t < 4; ++t)
            a[t] = *(const half8*)&A_lds[(wr * 64 + t * 16 + r15) * 32 + quad * 8];
#pragma unroll
        for (int u = 0; u < 4; ++u)
            bf[u] = *(const half8*)&B_lds[(wc * 64 + u * 16 + r15) * 32 + quad * 8];
#pragma unroll
        for (int t = 0; t < 4; ++t)
#pragma unroll
            for (int u = 0; u < 4; ++u) acc[t][u] = MFMA16(a[t], bf[u], acc[t][u]);
    }

    const int gc0 = bn * 128 + wc * 64;
    float bb[4];
#pragma unroll
    for (int u = 0; u < 4; ++u) bb[u] = bias[gc0 + u * 16 + r15];

#pragma unroll
    for (int t = 0; t < 4; ++t) {
#pragma unroll
        for (int u = 0; u < 4; ++u) {
            const int gc = gc0 + u * 16 + r15;
#pragma unroll
            for (int r = 0; r < 4; ++r) {
                const int grow = bm * 128 + wr * 64 + t * 16 + quad * 4 + r;
                const float val = acc[t][u][r] + bb[u];
                if constexpr (MODE == 0) {
                    const int hh = gc >> 6, dd = gc & 63;
                    const int b_ = grow >> 11, s = grow & 2047;
                    ((_Float16*)outp)[((size_t)((b_ * 16 + hh) * 2048 + s)) * 64 + dd] =
                        (_Float16)val;
                } else if constexpr (MODE == 2) {
                    const int hh = gc >> 6, dd = gc & 63;
                    const int b_ = grow >> 11, s = grow & 2047;
                    ((_Float16*)outp)[((size_t)((b_ * 16 + hh) * 64 + dd)) * 2048 + s] =
                        (_Float16)val;
                } else {
                    ((float*)outp)[(size_t)grow * 1024 + gc] = val;
                }
            }
        }
    }
}

// ---------------------------------------------------------------------------
// Attention: block = (b, h, 16 q-rows), 4 waves splitting keys (wv*16+r15).
// No K/V LDS staging: MFMA B-fragments are direct coalesced global loads
// (K row-major for QK^T; V pre-transposed [b,h,d,s] for PV).
// Phase 1: 2048 logits/q-row in regs (S[32] floatx4). Softmax via shuffle +
// tiny LDS cross-wave reduce. PV in 2 half-passes through a 33KB fp16 w_lds
// (-> 4 blocks/CU occupancy), with fp32 weight stores interleaved into the
// PV MFMA stream.  mask*1e-9 contribution dropped (<=1e-9 on O(1) logits).
// ---------------------------------------------------------------------------
__global__ __launch_bounds__(256, 2) void attn_kernel(
    const _Float16* __restrict__ Q, const _Float16* __restrict__ K,
    const _Float16* __restrict__ Vt, float* __restrict__ wout,
    _Float16* __restrict__ attn_out)
{
    __shared__ _Float16 w_lds[16 * 1032];   // 16 q-rows x 1024 keys (+8 pad)
    __shared__ float red[2][4][16];

    const int tid  = threadIdx.x;
    const int lane = tid & 63;
    const int wv   = tid >> 6;
    const int r15  = lane & 15;
    const int quad = lane >> 4;
    const int qb   = blockIdx.x;    // 0..127
    const int h    = blockIdx.y;
    const int b    = blockIdx.z;

    const size_t hoff = ((size_t)(b * 16 + h)) * S_LEN * DEPTH;
    const _Float16* Qh  = Q + hoff + (size_t)qb * 16 * DEPTH;
    const _Float16* Kh  = K + hoff;
    const _Float16* Vth = Vt + hoff;     // [d][s] layout per head

    half8 q0 = *(const half8*)(Qh + r15 * 64 + quad * 8);
    half8 q1 = *(const half8*)(Qh + r15 * 64 + 32 + quad * 8);

    // ---- Phase 1: logits, direct global B-fragments ----
    floatx4 S[32];
#pragma unroll
    for (int kt = 0; kt < 32; ++kt) {
        const _Float16* kp = Kh + (size_t)(kt * 64 + wv * 16 + r15) * 64 + quad * 8;
        half8 b0 = *(const half8*)kp;
        half8 b1 = *(const half8*)(kp + 32);
        floatx4 z = floatx4{0.f, 0.f, 0.f, 0.f};
        z = MFMA16(q0, b0, z);
        z = MFMA16(q1, b1, z);
        S[kt] = z;
    }

    // ---- Phase 2: softmax ----
    float pm[4] = {-1e30f, -1e30f, -1e30f, -1e30f};
#pragma unroll
    for (int kt = 0; kt < 32; ++kt)
#pragma unroll
        for (int j = 0; j < 4; ++j) {
            S[kt][j] *= 0.125f;                      // 1/sqrt(64)
            pm[j] = fmaxf(pm[j], S[kt][j]);
        }
#pragma unroll
    for (int m = 1; m <= 8; m <<= 1)
#pragma unroll
        for (int j = 0; j < 4; ++j) pm[j] = fmaxf(pm[j], __shfl_xor(pm[j], m, 64));
#pragma unroll
    for (int j = 0; j < 4; ++j)
        if (r15 == j) red[0][wv][quad * 4 + j] = pm[j];
    __syncthreads();
    float gm[4];
#pragma unroll
    for (int j = 0; j < 4; ++j) {
        int row = quad * 4 + j;
        gm[j] = fmaxf(fmaxf(red[0][0][row], red[0][1][row]),
                      fmaxf(red[0][2][row], red[0][3][row]));
    }
    float ps[4] = {0.f, 0.f, 0.f, 0.f};
#pragma unroll
    for (int kt = 0; kt < 32; ++kt)
#pragma unroll
        for (int j = 0; j < 4; ++j) {
            float e = __expf(S[kt][j] - gm[j]);
            S[kt][j] = e;
            ps[j] += e;
        }
#pragma unroll
    for (int m = 1; m <= 8; m <<= 1)
#pragma unroll
        for (int j = 0; j < 4; ++j) ps[j] += __shfl_xor(ps[j], m, 64);
#pragma unroll
    for (int j = 0; j < 4; ++j)
        if (r15 == j) red[1][wv][quad * 4 + j] = ps[j];
    __syncthreads();
    float gl[4];
#pragma unroll
    for (int j = 0; j < 4; ++j) {
        int row = quad * 4 + j;
        gl[j] = 1.0f / (red[1][0][row] + red[1][1][row] + red[1][2][row] + red[1][3][row]);
    }

    // ---- Phase 3: weights out + PV, two half-passes over keys ----
    float* wrow = wout + (((size_t)(b * 16 + h)) * S_LEN + (size_t)qb * 16) * S_LEN;
    floatx4 oacc = floatx4{0.f, 0.f, 0.f, 0.f};
#pragma unroll
    for (int hf = 0; hf < 2; ++hf) {
        // fp16 weights -> w_lds (C-layout source -> A-layout for PV)
#pragma unroll
        for (int k2 = 0; k2 < 16; ++k2) {
            const int kt = hf * 16 + k2;
#pragma unroll
            for (int j = 0; j < 4; ++j)
                w_lds[(quad * 4 + j) * 1032 + k2 * 64 + wv * 16 + r15] =
                    (_Float16)(S[kt][j] * gl[j]);
        }
        __syncthreads();
#pragma unroll
        for (int k2 = 0; k2 < 16; ++k2) {
            const int kt = hf * 16 + k2;
            // fp32 weight stores interleaved with PV MFMAs
#pragma unroll
            for (int j = 0; j < 4; ++j)
                wrow[(size_t)(quad * 4 + j) * 2048 + kt * 64 + wv * 16 + r15] =
                    S[kt][j] * gl[j];
            const _Float16* vp =
                Vth + (size_t)(wv * 16 + r15) * 2048 + (size_t)kt * 64 + quad * 8;
            half8 a0 = *(const half8*)&w_lds[r15 * 1032 + k2 * 64 + quad * 8];
            half8 a1 = *(const half8*)&w_lds[r15 * 1032 + k2 * 64 + 32 + quad * 8];
            half8 b0 = *(const half8*)vp;
            half8 b1 = *(const half8*)(vp + 32);
            oacc = MFMA16(a0, b0, oacc);
            oacc = MFMA16(a1, b1, oacc);
        }
        __syncthreads();
    }

    // attn output fp16, [b*2048+s][h*64+d]  (GEMM input for Wo)
    _Float16* ao = attn_out + ((size_t)(b * S_LEN + qb * 16)) * D_MODEL + h * 64 + wv * 16;
#pragma unroll
    for (int r = 0; r < 4; ++r)
        ao[(size_t)(quad * 4 + r) * D_MODEL + r15] = (_Float16)oacc[r];
}

// ---------------------------------------------------------------------------
extern "C" void kernel_launch(void* const* d_in, const int* in_sizes, int n_in,
                              void* d_out, int out_size, void* d_ws, size_t ws_size,
                              hipStream_t stream)
{
    const float* q  = (const float*)d_in[0];
    const float* k  = (const float*)d_in[1];
    const float* v  = (const float*)d_in[2];
    // d_in[3] = mask: mask*1e-9 <= 1e-9 on O(1) logits -> numerically dropped.
    const float* Wq = (const float*)d_in[4];
    const float* bq = (const float*)d_in[5];
    const float* Wk = (const float*)d_in[6];
    const float* bk = (const float*)d_in[7];
    const float* Wv = (const float*)d_in[8];
    const float* bv = (const float*)d_in[9];
    const float* Wo = (const float*)d_in[10];
    const float* bo = (const float*)d_in[11];

    const size_t NTOK = (size_t)BATCH * S_LEN * D_MODEL;   // 4194304
    const size_t WSZ  = (size_t)D_MODEL * D_MODEL;         // 1048576
    _Float16* base = (_Float16*)d_ws;
    _Float16* qh  = base;                 // fp16 X inputs (qh reused as Aw later)
    _Float16* kh  = base + NTOK;
    _Float16* vh  = base + 2 * NTOK;
    _Float16* Qw  = base + 3 * NTOK;      // projected Q [b,h,s,d]
    _Float16* Kw  = base + 4 * NTOK;      // projected K [b,h,s,d]
    _Float16* Vt  = base + 5 * NTOK;      // projected V [b,h,d,s]
    _Float16* Wqh = base + 6 * NTOK;
    _Float16* Wkh = Wqh + WSZ;
    _Float16* Wvh = Wkh + WSZ;
    _Float16* Woh = Wvh + WSZ;
    _Float16* Aw  = qh;                   // attention output (qh no longer needed)

    float* out  = (float*)d_out;          // [2,2048,1024]
    float* wout = out + NTOK;             // [2,16,2048,2048]

    dim3 blk(256);
    cvt_kernel<<<dim3(2048), blk, 0, stream>>>(q, qh, (int)(NTOK / 8));
    cvt_kernel<<<dim3(2048), blk, 0, stream>>>(k, kh, (int)(NTOK / 8));
    cvt_kernel<<<dim3(2048), blk, 0, stream>>>(v, vh, (int)(NTOK / 8));
    cvt_kernel<<<dim3(512),  blk, 0, stream>>>(Wq, Wqh, (int)(WSZ / 8));
    cvt_kernel<<<dim3(512),  blk, 0, stream>>>(Wk, Wkh, (int)(WSZ / 8));
    cvt_kernel<<<dim3(512),  blk, 0, stream>>>(Wv, Wvh, (int)(WSZ / 8));
    cvt_kernel<<<dim3(512),  blk, 0, stream>>>(Wo, Woh, (int)(WSZ / 8));

    dim3 ggrid(8, 32);
    gemm_kernel<0><<<ggrid, blk, 0, stream>>>(qh, Wqh, bq, (void*)Qw);
    gemm_kernel<0><<<ggrid, blk, 0, stream>>>(kh, Wkh, bk, (void*)Kw);
    gemm_kernel<2><<<ggrid, blk, 0, stream>>>(vh, Wvh, bv, (void*)Vt);

    attn_kernel<<<dim3(128, 16, 2), blk, 0, stream>>>(Qw, Kw, Vt, wout, Aw);

    gemm_kernel<1><<<ggrid, blk, 0, stream>>>(Aw, Woh, bo, (void*)out);
}